// Round 15
// baseline (236.912 us; speedup 1.0000x reference)
//
#include <hip/hip_runtime.h>
#include <hip/hip_fp16.h>
#include <math.h>

// GAT 2-layer. R28 = R27 resubmit (container failed twice; same infra failure
// mode previously resolved by unchanged resubmits in R23 — audit of the split
// plumbing found no fault class: uniform barriers, clamped ranges, guarded
// stores). VISIBILITY round: agg kernels split into two half-range dispatches
// (~25us each) so the top-5 window exposes the true kGB/kP2/gap cost (ladder
// says ~126us; roofline models say <=50us). R26 deterministic binning, R25
// fp16 logits + 8-wave fused TF1, gapped CSR all unchanged.

#define CAPS 16
#define CELL 48
#define NBMAX 512
#define BINB 256
#define REGION 7168           // gapped-CSR region per bucket (max ~4400 edges)
#define LOG2E 1.44269504f

typedef _Float16 h2_t  __attribute__((ext_vector_type(2)));
typedef _Float16 h8_t  __attribute__((ext_vector_type(8)));
typedef float    f4_t  __attribute__((ext_vector_type(4)));
typedef unsigned int u4_t __attribute__((ext_vector_type(4)));

__device__ __forceinline__ float lrelu(float v) { return v >= 0.f ? v : 0.2f * v; }
__device__ __forceinline__ float eluf(float v)  {
    return v > 0.f ? v : __builtin_amdgcn_exp2f(v * LOG2E) - 1.f;
}

// acc += (float)lo_half(pk) * w   /   acc += (float)hi_half(pk) * w
#define MIX_LO(acc, pk, w) asm("v_fma_mix_f32 %0, %1, %2, %0 op_sel:[0,0,0] op_sel_hi:[1,0,0]" : "+v"(acc) : "v"(pk), "v"(w))
#define MIX_HI(acc, pk, w) asm("v_fma_mix_f32 %0, %1, %2, %0 op_sel:[1,0,0] op_sel_hi:[1,0,0]" : "+v"(acc) : "v"(pk), "v"(w))

// ---------------- tf0 MFMA body: 8 waves/block(512), 16 rows/wave -------------
__device__ __forceinline__ void gemm_body(
    int gb, const float* __restrict__ x, int N,
    __half* __restrict__ xw, __half* __restrict__ as, __half* __restrict__ ad,
    h8_t* Bl)
{
    int wave = threadIdx.x >> 6, lane = threadIdx.x & 63;
    int row0 = gb * 128 + wave * 16;
    if (row0 >= N) return;
    int quad = lane >> 4, c16 = lane & 15;
    int myrow = min(row0 + c16, N - 1);
    const float* xr = x + (size_t)myrow * 128;
    h8_t a[4];
    #pragma unroll
    for (int ks = 0; ks < 4; ks++) {
        int kb = ks * 32 + quad * 8;
        float4 v0 = *(const float4*)(xr + kb);
        float4 v1 = *(const float4*)(xr + kb + 4);
        h8_t av;
        av[0] = (_Float16)v0.x; av[1] = (_Float16)v0.y;
        av[2] = (_Float16)v0.z; av[3] = (_Float16)v0.w;
        av[4] = (_Float16)v1.x; av[5] = (_Float16)v1.y;
        av[6] = (_Float16)v1.z; av[7] = (_Float16)v1.w;
        a[ks] = av;
    }
    int rbase = row0 + quad * 4;
    #pragma unroll
    for (int ct = 0; ct < 5; ct++) {
        f4_t acc = {0.f, 0.f, 0.f, 0.f};
        #pragma unroll
        for (int ks = 0; ks < 4; ks++) {
            h8_t b = Bl[(ct * 4 + ks) * 64 + lane];
            acc = __builtin_amdgcn_mfma_f32_16x16x32_f16(a[ks], b, acc, 0, 0, 0);
        }
        if (ct < 4) {
            int col = ct * 16 + c16;
            #pragma unroll
            for (int r = 0; r < 4; r++) {
                int row = rbase + r;
                if (row < N) xw[(size_t)row * 64 + col] = __float2half(acc[r]);
            }
        } else {
            #pragma unroll
            for (int r = 0; r < 4; r++) {
                int row = rbase + r;
                if (row < N) {
                    float sc = acc[r] * LOG2E;   // pre-scale logits: exp -> exp2
                    if (c16 < 8) as[(size_t)row * 8 + c16] = __float2half(sc);
                    else         ad[(size_t)row * 8 + (c16 - 8)] = __float2half(sc);
                }
            }
        }
    }
}

// ---------------- fused: gemm0 || deterministic single-pass binning ---------
__global__ __launch_bounds__(512, 4) void kGB(
    const float* __restrict__ x, const float* __restrict__ W0,
    const float* __restrict__ aS0, const float* __restrict__ aD0, int N,
    __half* __restrict__ xw, __half* __restrict__ as, __half* __restrict__ ad,
    int gemmBlocks,
    const int* __restrict__ src, const int* __restrict__ dst, int E, int perBlock,
    unsigned* __restrict__ bucketBuf, int* __restrict__ cntT,
    int NB, int binBlocks)
{
    __shared__ __align__(16) char smem[NBMAX * CAPS * 4 + NBMAX * 4]; // 34.8 KB union
    int b = blockIdx.x;
    int T = gemmBlocks + binBlocks;
    int lo = (int)((long long)b * gemmBlocks / T);
    int hi = (int)((long long)(b + 1) * gemmBlocks / T);
    if (hi > lo) {
        h8_t* Bl = (h8_t*)smem;
        for (int g = threadIdx.x; g < 1280; g += 512) {
            int col  = g & 15;
            int quad = (g >> 4) & 3;
            int ks   = (g >> 6) & 3;
            int ct   = g >> 8;
            h8_t av;
            if (ct < 4) {
                #pragma unroll
                for (int j = 0; j < 8; j++) {
                    int k = ks * 32 + quad * 8 + j;
                    av[j] = (_Float16)W0[k * 64 + ct * 16 + col];
                }
            } else {
                int h = col & 7;
                const float* att = (col < 8) ? aS0 : aD0;
                #pragma unroll
                for (int j = 0; j < 8; j++) {
                    int k = ks * 32 + quad * 8 + j;
                    float v = 0.f;
                    #pragma unroll
                    for (int cc = 0; cc < 8; cc++)
                        v += W0[k * 64 + h * 8 + cc] * att[h * 8 + cc];
                    av[j] = (_Float16)v;
                }
            }
            Bl[g] = av;
        }
        __syncthreads();
        gemm_body(lo, x, N, xw, as, ad, Bl);
    } else {
        int pb = b - hi;                                   // 0..BINB-1
        unsigned* stage = (unsigned*)smem;                 // [NBMAX][CAPS]
        int* scnt = (int*)(smem + NBMAX * CAPS * 4);
        int tid = threadIdx.x;
        for (int i = tid; i < NB; i += 512) scnt[i] = 0;
        __syncthreads();
        int e0 = pb * perBlock, e1 = min(E, e0 + perBlock);
        for (int i = e0 + tid; i < e1; i += 512) {
            int d2 = dst[i], s2 = src[i];
            int bk = d2 >> 8;                              // 256-node buckets
            unsigned rec = ((unsigned)(d2 & 255) << 22) | (unsigned)s2;
            int pos = atomicAdd(&scnt[bk], 1);
            if (pos < CAPS) {
                stage[bk * CAPS + pos] = rec;
            } else if (pos < CELL) {                       // deterministic spill
                bucketBuf[((size_t)bk * BINB + pb) * CELL + pos] = rec;
            }
        }
        __syncthreads();
        const uint4* stv = (const uint4*)stage;
        for (int t = tid; t < NB; t += 512) {
            int n = min(scnt[t], CELL);
            cntT[(size_t)pb * NBMAX + t] = n;              // coalesced
            uint4* gp = (uint4*)&bucketBuf[((size_t)t * BINB + pb) * CELL];
            gp[0] = stv[t * 4 + 0];                        // unconditional 64B;
            gp[1] = stv[t * 4 + 1];                        // slots >= n are garbage,
            gp[2] = stv[t * 4 + 2];                        // guarded by cntT in kP2
            gp[3] = stv[t * 4 + 3];
        }
    }
}

// ---------------- phase2: gapped-CSR build, shfl-scan, cell-major -----------
__global__ __launch_bounds__(256) void kP2(
    const unsigned* __restrict__ bucketBuf, const int* __restrict__ cntT,
    int NB, int N,
    int* __restrict__ rowS, int* __restrict__ rowE, int* __restrict__ adj)
{
    __shared__ int deg[256];
    __shared__ int curl[256];
    __shared__ int wsum[4];
    int b = blockIdx.x, tid = threadIdx.x;
    int lo = b << 8;
    int hi = min(N, lo + 256);
    int cnt = hi - lo;
    int myc = cntT[(size_t)tid * NBMAX + b];               // tid = cell (BINB=256)
    deg[tid] = 0;
    __syncthreads();
    const unsigned* buf = bucketBuf + (size_t)b * BINB * CELL;
    {
        const unsigned* p = buf + tid * CELL;
        for (int i = 0; i < myc; i++) atomicAdd(&deg[p[i] >> 22], 1);
    }
    __syncthreads();
    int d = deg[tid];
    // exclusive prefix over 256 via wave shfl scan + cross-wave fix
    int lane = tid & 63, wid = tid >> 6;
    int x = d;
    #pragma unroll
    for (int off = 1; off < 64; off <<= 1) {
        int y = __shfl_up(x, off, 64);
        if (lane >= off) x += y;
    }
    if (lane == 63) wsum[wid] = x;
    __syncthreads();
    int add = 0;
    #pragma unroll
    for (int w = 0; w < 4; w++) add += (w < wid) ? wsum[w] : 0;
    int excl = x + add - d;
    int base = b * REGION;                                 // gapped CSR region
    curl[tid] = base + excl;
    if (tid < cnt) { rowS[lo + tid] = base + excl; rowE[lo + tid] = base + excl + d; }
    __syncthreads();
    {
        const unsigned* p = buf + tid * CELL;
        for (int i = 0; i < myc; i++) {
            unsigned r = p[i];
            int pp = atomicAdd(&curl[r >> 22], 1);
            adj[pp] = (int)(r & 0x3FFFFF);
        }
    }
}

// ---------------- layer0 agg (4 nodes/wave) + 8-wave fused TF1 -------------
// Processes node range [n0, n1) — split across two dispatches for profiler
// visibility (R27); block tiling unchanged (n0 is a multiple of 32).
__global__ __launch_bounds__(512) void k_agg8(
    const __half* __restrict__ xw, const __half* __restrict__ as, const __half* __restrict__ ad,
    const int* __restrict__ rowS, const int* __restrict__ rowE, const int* __restrict__ adj,
    const float* __restrict__ bias,
    const float* __restrict__ W1, const float* __restrict__ aS1, const float* __restrict__ aD1,
    int n0, int n1, int N,
    __half* __restrict__ hw, float* __restrict__ as1, float* __restrict__ ad1)
{
    __shared__ __align__(16) h8_t Wl[512];     // W1 image [ct][ks][quad][col]
    __shared__ __align__(16) h8_t hst[32][9];  // h chunks, padded stride
    __shared__ float psum[4][32];
    __shared__ float pdsum[4][32];
    {
        int g = threadIdx.x;
        int col  = g & 15;
        int quad = (g >> 4) & 3;
        int ks   = (g >> 6) & 1;
        int ct   = g >> 7;
        h8_t av;
        #pragma unroll
        for (int j = 0; j < 8; j++) {
            int k = ks * 32 + quad * 8 + j;
            av[j] = (_Float16)W1[k * 64 + ct * 16 + col];
        }
        Wl[g] = av;
    }
    int n = n0 + ((blockIdx.x * 512 + threadIdx.x) >> 4);   // 32 nodes per block
    int sub  = threadIdx.x & 15;
    bool active = n < n1;
    int e2 = sub >> 3;
    int hh = sub & 7;
    int rs = active ? rowS[n] : 0;
    int re = active ? rowE[n] : 0;
    const u4_t* xwv = (const u4_t*)xw;               // row stride = 8 chunks
    unsigned nc = active ? (unsigned)n : 0u;
    float adv = __half2float(ad[nc * 8u + hh]);
    float shift = lrelu(__half2float(as[nc * 8u + hh]) + adv);
    float accv[8];
    #pragma unroll
    for (int k = 0; k < 8; k++) accv[k] = 0.f;
    float dsum = 0.f;

    int j = rs;
    bool vA0 = j + e2 < re,     vB0 = j + 2 + e2 < re;
    int  sA0 = adj[(unsigned)(vA0 ? j + e2 : 0)];
    int  sB0 = adj[(unsigned)(vB0 ? j + 2 + e2 : 0)];
    bool vA1 = j + 4 + e2 < re, vB1 = j + 6 + e2 < re;
    int  sA1 = adj[(unsigned)(vA1 ? j + 4 + e2 : 0)];
    int  sB1 = adj[(unsigned)(vB1 ? j + 6 + e2 : 0)];
    float eA0 = lrelu(__half2float(as[(unsigned)sA0 * 8u + hh]) + adv);
    float eB0 = lrelu(__half2float(as[(unsigned)sB0 * 8u + hh]) + adv);
    u4_t xA0 = xwv[(unsigned)sA0 * 8u + hh];
    u4_t xB0 = xwv[(unsigned)sB0 * 8u + hh];
    float eA1, eB1; u4_t xA1, xB1;

    for (;;) {
        // phase even: prefetch adj(j+8)->slot0, gathers slot1, compute slot0
        {
            bool vA2 = j + 8 + e2 < re, vB2 = j + 10 + e2 < re;
            int nsA = adj[(unsigned)(vA2 ? j + 8 + e2 : 0)];
            int nsB = adj[(unsigned)(vB2 ? j + 10 + e2 : 0)];
            eA1 = lrelu(__half2float(as[(unsigned)sA1 * 8u + hh]) + adv);
            eB1 = lrelu(__half2float(as[(unsigned)sB1 * 8u + hh]) + adv);
            xA1 = xwv[(unsigned)sA1 * 8u + hh];
            xB1 = xwv[(unsigned)sB1 * 8u + hh];
            float wA = vA0 ? __builtin_amdgcn_exp2f(eA0 - shift) : 0.f;
            float wB = vB0 ? __builtin_amdgcn_exp2f(eB0 - shift) : 0.f;
            dsum += wA + wB;
            #pragma unroll
            for (int q = 0; q < 4; q++) {
                MIX_LO(accv[2 * q],     xA0[q], wA);
                MIX_HI(accv[2 * q + 1], xA0[q], wA);
            }
            #pragma unroll
            for (int q = 0; q < 4; q++) {
                MIX_LO(accv[2 * q],     xB0[q], wB);
                MIX_HI(accv[2 * q + 1], xB0[q], wB);
            }
            vA0 = vA2; vB0 = vB2; sA0 = nsA; sB0 = nsB;
        }
        j += 4;
        if (!__any(vA1)) break;
        // phase odd: prefetch adj(j+8)->slot1, gathers slot0, compute slot1
        {
            bool vA2 = j + 8 + e2 < re, vB2 = j + 10 + e2 < re;
            int nsA = adj[(unsigned)(vA2 ? j + 8 + e2 : 0)];
            int nsB = adj[(unsigned)(vB2 ? j + 10 + e2 : 0)];
            eA0 = lrelu(__half2float(as[(unsigned)sA0 * 8u + hh]) + adv);
            eB0 = lrelu(__half2float(as[(unsigned)sB0 * 8u + hh]) + adv);
            xA0 = xwv[(unsigned)sA0 * 8u + hh];
            xB0 = xwv[(unsigned)sB0 * 8u + hh];
            float wA = vA1 ? __builtin_amdgcn_exp2f(eA1 - shift) : 0.f;
            float wB = vB1 ? __builtin_amdgcn_exp2f(eB1 - shift) : 0.f;
            dsum += wA + wB;
            #pragma unroll
            for (int q = 0; q < 4; q++) {
                MIX_LO(accv[2 * q],     xA1[q], wA);
                MIX_HI(accv[2 * q + 1], xA1[q], wA);
            }
            #pragma unroll
            for (int q = 0; q < 4; q++) {
                MIX_LO(accv[2 * q],     xB1[q], wB);
                MIX_HI(accv[2 * q + 1], xB1[q], wB);
            }
            vA1 = vA2; vB1 = vB2; sA1 = nsA; sB1 = nsB;
        }
        j += 4;
        if (!__any(vA0)) break;
    }
    #pragma unroll
    for (int k = 0; k < 8; k++) accv[k] += __shfl_xor(accv[k], 8, 64);
    dsum += __shfl_xor(dsum, 8, 64);
    if (e2 == 0) {
        int nl = (threadIdx.x >> 4);                 // local node 0..31
        h8_t o;
        if (active) {
            float inv = 1.f / (1.f + dsum);          // self-loop weight = 1
            h8_t sv = *(const h8_t*)(xw + (size_t)n * 64 + hh * 8);
            float4 b0 = *(const float4*)(bias + hh * 8);
            float4 b1 = *(const float4*)(bias + hh * 8 + 4);
            float bb[8] = {b0.x, b0.y, b0.z, b0.w, b1.x, b1.y, b1.z, b1.w};
            #pragma unroll
            for (int k = 0; k < 8; k++) {
                float v = (accv[k] + (float)sv[k]) * inv + bb[k];
                o[k] = (_Float16)eluf(v);
            }
        } else {
            #pragma unroll
            for (int k = 0; k < 8; k++) o[k] = (_Float16)0.f;
        }
        hst[nl][hh] = o;
    }
    __syncthreads();
    // ---- fused TF1 across all 8 waves: wave w -> ct=w>>1 (cols), half=w&1 (rows)
    {
        int wave = threadIdx.x >> 6, lane = threadIdx.x & 63;
        int ct   = wave >> 1;
        int half = wave & 1;
        int quad = lane >> 4, c16 = lane & 15;
        int lrow = half * 16 + c16;                  // local row 0..31
        int row0 = n0 + blockIdx.x * 32 + half * 16;
        h8_t a0 = hst[lrow][quad];
        h8_t a1 = hst[lrow][4 + quad];
        int rbase = row0 + quad * 4;
        f4_t acc = {0.f, 0.f, 0.f, 0.f};
        acc = __builtin_amdgcn_mfma_f32_16x16x32_f16(a0, Wl[(ct * 2 + 0) * 64 + lane], acc, 0, 0, 0);
        acc = __builtin_amdgcn_mfma_f32_16x16x32_f16(a1, Wl[(ct * 2 + 1) * 64 + lane], acc, 0, 0, 0);
        float s1c = aS1[ct * 16 + c16];
        float d1c = aD1[ct * 16 + c16];
        int col = ct * 16 + c16;
        float ps[4], pd[4];
        #pragma unroll
        for (int r = 0; r < 4; r++) {
            int rr = rbase + r;
            if (rr < n1) hw[(size_t)rr * 64 + col] = __float2half(acc[r]);
            ps[r] = acc[r] * s1c;
            pd[r] = acc[r] * d1c;
        }
        #pragma unroll
        for (int r = 0; r < 4; r++) {
            #pragma unroll
            for (int off = 1; off < 16; off <<= 1) {
                ps[r] += __shfl_xor(ps[r], off, 64);
                pd[r] += __shfl_xor(pd[r], off, 64);
            }
        }
        if (c16 == 0) {
            #pragma unroll
            for (int r = 0; r < 4; r++) {
                int lr = half * 16 + quad * 4 + r;
                psum[ct][lr]  = ps[r];
                pdsum[ct][lr] = pd[r];
            }
        }
    }
    __syncthreads();
    if (threadIdx.x < 32) {
        int lr = threadIdx.x;
        int rr = n0 + blockIdx.x * 32 + lr;
        if (rr < n1) {
            float s  = psum[0][lr] + psum[1][lr] + psum[2][lr] + psum[3][lr];
            float dd = pdsum[0][lr] + pdsum[1][lr] + pdsum[2][lr] + pdsum[3][lr];
            as1[rr] = s * LOG2E;
            ad1[rr] = dd * LOG2E;
        }
    }
}

// ---------------- layer1 aggregation: 4 nodes/wave, node range [n0,n1) ------
__global__ __launch_bounds__(512) void k_agg1(
    const __half* __restrict__ hw, const float* __restrict__ as, const float* __restrict__ ad,
    const int* __restrict__ rowS, const int* __restrict__ rowE, const int* __restrict__ adj,
    const float* __restrict__ bias, int n0, int n1, float* __restrict__ outp)
{
    int n = n0 + ((blockIdx.x * 512 + threadIdx.x) >> 4);   // 32 nodes per block
    int sub  = threadIdx.x & 15;
    if (n >= n1) return;
    int e2 = sub >> 3;
    int hh = sub & 7;
    int rs = rowS[n], re = rowE[n];
    const u4_t* hwv = (const u4_t*)hw;
    float adv = ad[n];
    float shift = lrelu(as[n] + adv);
    float accv[8];
    #pragma unroll
    for (int k = 0; k < 8; k++) accv[k] = 0.f;
    float dsum = 0.f;

    int j = rs;
    bool vA0 = j + e2 < re,     vB0 = j + 2 + e2 < re;
    int  sA0 = adj[(unsigned)(vA0 ? j + e2 : 0)];
    int  sB0 = adj[(unsigned)(vB0 ? j + 2 + e2 : 0)];
    bool vA1 = j + 4 + e2 < re, vB1 = j + 6 + e2 < re;
    int  sA1 = adj[(unsigned)(vA1 ? j + 4 + e2 : 0)];
    int  sB1 = adj[(unsigned)(vB1 ? j + 6 + e2 : 0)];
    float eA0 = lrelu(as[(unsigned)sA0] + adv);
    float eB0 = lrelu(as[(unsigned)sB0] + adv);
    u4_t xA0 = hwv[(unsigned)sA0 * 8u + hh];
    u4_t xB0 = hwv[(unsigned)sB0 * 8u + hh];
    float eA1, eB1; u4_t xA1, xB1;

    for (;;) {
        // phase even
        {
            bool vA2 = j + 8 + e2 < re, vB2 = j + 10 + e2 < re;
            int nsA = adj[(unsigned)(vA2 ? j + 8 + e2 : 0)];
            int nsB = adj[(unsigned)(vB2 ? j + 10 + e2 : 0)];
            eA1 = lrelu(as[(unsigned)sA1] + adv);
            eB1 = lrelu(as[(unsigned)sB1] + adv);
            xA1 = hwv[(unsigned)sA1 * 8u + hh];
            xB1 = hwv[(unsigned)sB1 * 8u + hh];
            float wA = vA0 ? __builtin_amdgcn_exp2f(eA0 - shift) : 0.f;
            float wB = vB0 ? __builtin_amdgcn_exp2f(eB0 - shift) : 0.f;
            dsum += wA + wB;
            #pragma unroll
            for (int q = 0; q < 4; q++) {
                MIX_LO(accv[2 * q],     xA0[q], wA);
                MIX_HI(accv[2 * q + 1], xA0[q], wA);
            }
            #pragma unroll
            for (int q = 0; q < 4; q++) {
                MIX_LO(accv[2 * q],     xB0[q], wB);
                MIX_HI(accv[2 * q + 1], xB0[q], wB);
            }
            vA0 = vA2; vB0 = vB2; sA0 = nsA; sB0 = nsB;
        }
        j += 4;
        if (!__any(vA1)) break;
        // phase odd
        {
            bool vA2 = j + 8 + e2 < re, vB2 = j + 10 + e2 < re;
            int nsA = adj[(unsigned)(vA2 ? j + 8 + e2 : 0)];
            int nsB = adj[(unsigned)(vB2 ? j + 10 + e2 : 0)];
            eA0 = lrelu(as[(unsigned)sA0] + adv);
            eB0 = lrelu(as[(unsigned)sB0] + adv);
            xA0 = hwv[(unsigned)sA0 * 8u + hh];
            xB0 = hwv[(unsigned)sB0 * 8u + hh];
            float wA = vA1 ? __builtin_amdgcn_exp2f(eA1 - shift) : 0.f;
            float wB = vB1 ? __builtin_amdgcn_exp2f(eB1 - shift) : 0.f;
            dsum += wA + wB;
            #pragma unroll
            for (int q = 0; q < 4; q++) {
                MIX_LO(accv[2 * q],     xA1[q], wA);
                MIX_HI(accv[2 * q + 1], xA1[q], wA);
            }
            #pragma unroll
            for (int q = 0; q < 4; q++) {
                MIX_LO(accv[2 * q],     xB1[q], wB);
                MIX_HI(accv[2 * q + 1], xB1[q], wB);
            }
            vA1 = vA2; vB1 = vB2; sA1 = nsA; sB1 = nsB;
        }
        j += 4;
        if (!__any(vA0)) break;
    }
    #pragma unroll
    for (int k = 0; k < 8; k++) accv[k] += __shfl_xor(accv[k], 8, 64);
    dsum += __shfl_xor(dsum, 8, 64);
    if (e2 == 0) {
        float inv = 1.f / (1.f + dsum);
        h8_t sv = *(const h8_t*)(hw + (size_t)n * 64 + hh * 8);
        float4 b0 = *(const float4*)(bias + hh * 8);
        float4 b1 = *(const float4*)(bias + hh * 8 + 4);
        float bb[8] = {b0.x, b0.y, b0.z, b0.w, b1.x, b1.y, b1.z, b1.w};
        float ov[8];
        #pragma unroll
        for (int k = 0; k < 8; k++)
            ov[k] = eluf((accv[k] + (float)sv[k]) * inv + bb[k]);
        float4 o0 = {ov[0], ov[1], ov[2], ov[3]};
        float4 o1 = {ov[4], ov[5], ov[6], ov[7]};
        float4* op = (float4*)(outp + (size_t)n * 64 + hh * 8);
        op[0] = o0;
        op[1] = o1;
    }
}

extern "C" void kernel_launch(void* const* d_in, const int* in_sizes, int n_in,
                              void* d_out, int out_size, void* d_ws, size_t ws_size,
                              hipStream_t stream)
{
    const float* x   = (const float*)d_in[0];
    const int*   ei  = (const int*)d_in[1];
    const float* W0  = (const float*)d_in[2];
    const float* aS0 = (const float*)d_in[3];
    const float* aD0 = (const float*)d_in[4];
    const float* b0  = (const float*)d_in[5];
    const float* W1  = (const float*)d_in[6];
    const float* aS1 = (const float*)d_in[7];
    const float* aD1 = (const float*)d_in[8];
    const float* b1  = (const float*)d_in[9];

    const int N = in_sizes[0] / 128;
    const int E = in_sizes[1] / 2;
    const int* srcp = ei;
    const int* dstp = ei + E;

    const int NB  = (N + 255) >> 8;          // 256-node buckets

    char* ws = (char*)d_ws;
    size_t off = 0;
    auto alloc = [&](size_t bytes) -> size_t {
        size_t o = off;
        off = (o + bytes + 255) & ~(size_t)255;
        return o;
    };
    __half* B1 = (__half*)(ws + alloc((size_t)N * 64 * 2));     // xw (half)
    size_t b2Bytes = (size_t)N * 64 * 2;
    size_t bkBytes = (size_t)NB * BINB * CELL * 4;              // 19.2 MB
    char*  region  = ws + alloc(b2Bytes > bkBytes ? b2Bytes : bkBytes);
    __half*   B2        = (__half*)region;     // hw overlays bucketBuf (dead after kP2)
    unsigned* bucketBuf = (unsigned*)region;
    __half* as0 = (__half*)(ws + alloc((size_t)N * 8 * 2));     // fp16 logits
    __half* ad0 = (__half*)(ws + alloc((size_t)N * 8 * 2));
    float* as1 = (float*)(ws + alloc((size_t)N * 4));
    float* ad1 = (float*)(ws + alloc((size_t)N * 4));
    int*  rowS = (int*)(ws + alloc((size_t)(N + 1) * 4));
    int*  rowE = (int*)(ws + alloc((size_t)(N + 1) * 4));
    int*   adj = (int*)(ws + alloc((size_t)NB * REGION * 4));
    int*  cntT = (int*)(ws + alloc((size_t)BINB * NBMAX * 4));

    const int gemmBlocks = (N + 127) / 128;
    const int binBlocks  = BINB;             // kP2 reads BINB cells per bucket
    const int perBlock   = (E + binBlocks - 1) / binBlocks;

    kGB<<<gemmBlocks + binBlocks, 512, 0, stream>>>(
        x, W0, aS0, aD0, N, B1, as0, ad0, gemmBlocks,
        srcp, dstp, E, perBlock, bucketBuf, cntT, NB, binBlocks);
    kP2<<<NB, 256, 0, stream>>>(bucketBuf, cntT, NB, N, rowS, rowE, adj);

    // split each agg into two half-range dispatches (~25us each) so the
    // profiler's top-5 window exposes kGB/kP2/gap costs (R27 visibility)
    const int nh = ((N / 2) + 31) & ~31;     // split point, multiple of 32
    const int blkA = (nh + 31) / 32;
    const int blkB = (N - nh + 31) / 32;
    k_agg8<<<blkA, 512, 0, stream>>>(B1, as0, ad0, rowS, rowE, adj, b0,
                                     W1, aS1, aD1, 0, nh, N, B2, as1, ad1);
    k_agg8<<<blkB, 512, 0, stream>>>(B1, as0, ad0, rowS, rowE, adj, b0,
                                     W1, aS1, aD1, nh, N, N, B2, as1, ad1);
    k_agg1<<<blkA, 512, 0, stream>>>(B2, as1, ad1, rowS, rowE, adj, b1, 0, nh, (float*)d_out);
    k_agg1<<<blkB, 512, 0, stream>>>(B2, as1, ad1, rowS, rowE, adj, b1, nh, N, (float*)d_out);
}

// Round 16
// 223.462 us; speedup vs baseline: 1.0602x; 1.0602x over previous
//
#include <hip/hip_runtime.h>
#include <hip/hip_fp16.h>
#include <math.h>

// GAT 2-layer. R29 = exact revert to R26 (224.5us) after R27/R28's visibility
// experiment. FINDING: the ~85us "hole" is __amd_rocclr_fillBufferAligned —
// the harness's per-iteration 256MiB workspace re-poison at 6.5TB/s, inside
// the timed window and untouchable from kernel code. The R27 agg split itself
// cost ~12us (extra dispatch tails) — reverted. Kernel-attributable time
// (~136us) is within ~5us of component floors: agg kernels at the ~3.3TB/s
// random-gather floor (R19-R21 triangulation), kGB stream-bound, kP2 ~8us.
// Structure: R26 deterministic binning (no atomics, no memset), R25 fp16
// logits + 8-wave fused TF1 epilogue, gapped CSR, 4 dispatches total.

#define CAPS 16
#define CELL 48
#define NBMAX 512
#define BINB 256
#define REGION 7168           // gapped-CSR region per bucket (max ~4400 edges)
#define LOG2E 1.44269504f

typedef _Float16 h2_t  __attribute__((ext_vector_type(2)));
typedef _Float16 h8_t  __attribute__((ext_vector_type(8)));
typedef float    f4_t  __attribute__((ext_vector_type(4)));
typedef unsigned int u4_t __attribute__((ext_vector_type(4)));

__device__ __forceinline__ float lrelu(float v) { return v >= 0.f ? v : 0.2f * v; }
__device__ __forceinline__ float eluf(float v)  {
    return v > 0.f ? v : __builtin_amdgcn_exp2f(v * LOG2E) - 1.f;
}

// acc += (float)lo_half(pk) * w   /   acc += (float)hi_half(pk) * w
#define MIX_LO(acc, pk, w) asm("v_fma_mix_f32 %0, %1, %2, %0 op_sel:[0,0,0] op_sel_hi:[1,0,0]" : "+v"(acc) : "v"(pk), "v"(w))
#define MIX_HI(acc, pk, w) asm("v_fma_mix_f32 %0, %1, %2, %0 op_sel:[1,0,0] op_sel_hi:[1,0,0]" : "+v"(acc) : "v"(pk), "v"(w))

// ---------------- tf0 MFMA body: 8 waves/block(512), 16 rows/wave -------------
__device__ __forceinline__ void gemm_body(
    int gb, const float* __restrict__ x, int N,
    __half* __restrict__ xw, __half* __restrict__ as, __half* __restrict__ ad,
    h8_t* Bl)
{
    int wave = threadIdx.x >> 6, lane = threadIdx.x & 63;
    int row0 = gb * 128 + wave * 16;
    if (row0 >= N) return;
    int quad = lane >> 4, c16 = lane & 15;
    int myrow = min(row0 + c16, N - 1);
    const float* xr = x + (size_t)myrow * 128;
    h8_t a[4];
    #pragma unroll
    for (int ks = 0; ks < 4; ks++) {
        int kb = ks * 32 + quad * 8;
        float4 v0 = *(const float4*)(xr + kb);
        float4 v1 = *(const float4*)(xr + kb + 4);
        h8_t av;
        av[0] = (_Float16)v0.x; av[1] = (_Float16)v0.y;
        av[2] = (_Float16)v0.z; av[3] = (_Float16)v0.w;
        av[4] = (_Float16)v1.x; av[5] = (_Float16)v1.y;
        av[6] = (_Float16)v1.z; av[7] = (_Float16)v1.w;
        a[ks] = av;
    }
    int rbase = row0 + quad * 4;
    #pragma unroll
    for (int ct = 0; ct < 5; ct++) {
        f4_t acc = {0.f, 0.f, 0.f, 0.f};
        #pragma unroll
        for (int ks = 0; ks < 4; ks++) {
            h8_t b = Bl[(ct * 4 + ks) * 64 + lane];
            acc = __builtin_amdgcn_mfma_f32_16x16x32_f16(a[ks], b, acc, 0, 0, 0);
        }
        if (ct < 4) {
            int col = ct * 16 + c16;
            #pragma unroll
            for (int r = 0; r < 4; r++) {
                int row = rbase + r;
                if (row < N) xw[(size_t)row * 64 + col] = __float2half(acc[r]);
            }
        } else {
            #pragma unroll
            for (int r = 0; r < 4; r++) {
                int row = rbase + r;
                if (row < N) {
                    float sc = acc[r] * LOG2E;   // pre-scale logits: exp -> exp2
                    if (c16 < 8) as[(size_t)row * 8 + c16] = __float2half(sc);
                    else         ad[(size_t)row * 8 + (c16 - 8)] = __float2half(sc);
                }
            }
        }
    }
}

// ---------------- fused: gemm0 || deterministic single-pass binning ---------
__global__ __launch_bounds__(512, 4) void kGB(
    const float* __restrict__ x, const float* __restrict__ W0,
    const float* __restrict__ aS0, const float* __restrict__ aD0, int N,
    __half* __restrict__ xw, __half* __restrict__ as, __half* __restrict__ ad,
    int gemmBlocks,
    const int* __restrict__ src, const int* __restrict__ dst, int E, int perBlock,
    unsigned* __restrict__ bucketBuf, int* __restrict__ cntT,
    int NB, int binBlocks)
{
    __shared__ __align__(16) char smem[NBMAX * CAPS * 4 + NBMAX * 4]; // 34.8 KB union
    int b = blockIdx.x;
    int T = gemmBlocks + binBlocks;
    int lo = (int)((long long)b * gemmBlocks / T);
    int hi = (int)((long long)(b + 1) * gemmBlocks / T);
    if (hi > lo) {
        h8_t* Bl = (h8_t*)smem;
        for (int g = threadIdx.x; g < 1280; g += 512) {
            int col  = g & 15;
            int quad = (g >> 4) & 3;
            int ks   = (g >> 6) & 3;
            int ct   = g >> 8;
            h8_t av;
            if (ct < 4) {
                #pragma unroll
                for (int j = 0; j < 8; j++) {
                    int k = ks * 32 + quad * 8 + j;
                    av[j] = (_Float16)W0[k * 64 + ct * 16 + col];
                }
            } else {
                int h = col & 7;
                const float* att = (col < 8) ? aS0 : aD0;
                #pragma unroll
                for (int j = 0; j < 8; j++) {
                    int k = ks * 32 + quad * 8 + j;
                    float v = 0.f;
                    #pragma unroll
                    for (int cc = 0; cc < 8; cc++)
                        v += W0[k * 64 + h * 8 + cc] * att[h * 8 + cc];
                    av[j] = (_Float16)v;
                }
            }
            Bl[g] = av;
        }
        __syncthreads();
        gemm_body(lo, x, N, xw, as, ad, Bl);
    } else {
        int pb = b - hi;                                   // 0..BINB-1
        unsigned* stage = (unsigned*)smem;                 // [NBMAX][CAPS]
        int* scnt = (int*)(smem + NBMAX * CAPS * 4);
        int tid = threadIdx.x;
        for (int i = tid; i < NB; i += 512) scnt[i] = 0;
        __syncthreads();
        int e0 = pb * perBlock, e1 = min(E, e0 + perBlock);
        for (int i = e0 + tid; i < e1; i += 512) {
            int d2 = dst[i], s2 = src[i];
            int bk = d2 >> 8;                              // 256-node buckets
            unsigned rec = ((unsigned)(d2 & 255) << 22) | (unsigned)s2;
            int pos = atomicAdd(&scnt[bk], 1);
            if (pos < CAPS) {
                stage[bk * CAPS + pos] = rec;
            } else if (pos < CELL) {                       // deterministic spill
                bucketBuf[((size_t)bk * BINB + pb) * CELL + pos] = rec;
            }
        }
        __syncthreads();
        const uint4* stv = (const uint4*)stage;
        for (int t = tid; t < NB; t += 512) {
            int n = min(scnt[t], CELL);
            cntT[(size_t)pb * NBMAX + t] = n;              // coalesced
            uint4* gp = (uint4*)&bucketBuf[((size_t)t * BINB + pb) * CELL];
            gp[0] = stv[t * 4 + 0];                        // unconditional 64B;
            gp[1] = stv[t * 4 + 1];                        // slots >= n are garbage,
            gp[2] = stv[t * 4 + 2];                        // guarded by cntT in kP2
            gp[3] = stv[t * 4 + 3];
        }
    }
}

// ---------------- phase2: gapped-CSR build, shfl-scan, cell-major -----------
__global__ __launch_bounds__(256) void kP2(
    const unsigned* __restrict__ bucketBuf, const int* __restrict__ cntT,
    int NB, int N,
    int* __restrict__ rowS, int* __restrict__ rowE, int* __restrict__ adj)
{
    __shared__ int deg[256];
    __shared__ int curl[256];
    __shared__ int wsum[4];
    int b = blockIdx.x, tid = threadIdx.x;
    int lo = b << 8;
    int hi = min(N, lo + 256);
    int cnt = hi - lo;
    int myc = cntT[(size_t)tid * NBMAX + b];               // tid = cell (BINB=256)
    deg[tid] = 0;
    __syncthreads();
    const unsigned* buf = bucketBuf + (size_t)b * BINB * CELL;
    {
        const unsigned* p = buf + tid * CELL;
        for (int i = 0; i < myc; i++) atomicAdd(&deg[p[i] >> 22], 1);
    }
    __syncthreads();
    int d = deg[tid];
    // exclusive prefix over 256 via wave shfl scan + cross-wave fix
    int lane = tid & 63, wid = tid >> 6;
    int x = d;
    #pragma unroll
    for (int off = 1; off < 64; off <<= 1) {
        int y = __shfl_up(x, off, 64);
        if (lane >= off) x += y;
    }
    if (lane == 63) wsum[wid] = x;
    __syncthreads();
    int add = 0;
    #pragma unroll
    for (int w = 0; w < 4; w++) add += (w < wid) ? wsum[w] : 0;
    int excl = x + add - d;
    int base = b * REGION;                                 // gapped CSR region
    curl[tid] = base + excl;
    if (tid < cnt) { rowS[lo + tid] = base + excl; rowE[lo + tid] = base + excl + d; }
    __syncthreads();
    {
        const unsigned* p = buf + tid * CELL;
        for (int i = 0; i < myc; i++) {
            unsigned r = p[i];
            int pp = atomicAdd(&curl[r >> 22], 1);
            adj[pp] = (int)(r & 0x3FFFFF);
        }
    }
}

// ---------------- layer0 agg (4 nodes/wave) + 8-wave fused TF1 -------------
__global__ __launch_bounds__(512) void k_agg8(
    const __half* __restrict__ xw, const __half* __restrict__ as, const __half* __restrict__ ad,
    const int* __restrict__ rowS, const int* __restrict__ rowE, const int* __restrict__ adj,
    const float* __restrict__ bias,
    const float* __restrict__ W1, const float* __restrict__ aS1, const float* __restrict__ aD1,
    int N, __half* __restrict__ hw, float* __restrict__ as1, float* __restrict__ ad1)
{
    __shared__ __align__(16) h8_t Wl[512];     // W1 image [ct][ks][quad][col]
    __shared__ __align__(16) h8_t hst[32][9];  // h chunks, padded stride
    __shared__ float psum[4][32];
    __shared__ float pdsum[4][32];
    {
        int g = threadIdx.x;
        int col  = g & 15;
        int quad = (g >> 4) & 3;
        int ks   = (g >> 6) & 1;
        int ct   = g >> 7;
        h8_t av;
        #pragma unroll
        for (int j = 0; j < 8; j++) {
            int k = ks * 32 + quad * 8 + j;
            av[j] = (_Float16)W1[k * 64 + ct * 16 + col];
        }
        Wl[g] = av;
    }
    int n = (blockIdx.x * 512 + threadIdx.x) >> 4;   // 32 nodes per block
    int sub  = threadIdx.x & 15;
    bool active = n < N;
    int e2 = sub >> 3;
    int hh = sub & 7;
    int rs = active ? rowS[n] : 0;
    int re = active ? rowE[n] : 0;
    const u4_t* xwv = (const u4_t*)xw;               // row stride = 8 chunks
    unsigned nc = active ? (unsigned)n : 0u;
    float adv = __half2float(ad[nc * 8u + hh]);
    float shift = lrelu(__half2float(as[nc * 8u + hh]) + adv);
    float accv[8];
    #pragma unroll
    for (int k = 0; k < 8; k++) accv[k] = 0.f;
    float dsum = 0.f;

    int j = rs;
    bool vA0 = j + e2 < re,     vB0 = j + 2 + e2 < re;
    int  sA0 = adj[(unsigned)(vA0 ? j + e2 : 0)];
    int  sB0 = adj[(unsigned)(vB0 ? j + 2 + e2 : 0)];
    bool vA1 = j + 4 + e2 < re, vB1 = j + 6 + e2 < re;
    int  sA1 = adj[(unsigned)(vA1 ? j + 4 + e2 : 0)];
    int  sB1 = adj[(unsigned)(vB1 ? j + 6 + e2 : 0)];
    float eA0 = lrelu(__half2float(as[(unsigned)sA0 * 8u + hh]) + adv);
    float eB0 = lrelu(__half2float(as[(unsigned)sB0 * 8u + hh]) + adv);
    u4_t xA0 = xwv[(unsigned)sA0 * 8u + hh];
    u4_t xB0 = xwv[(unsigned)sB0 * 8u + hh];
    float eA1, eB1; u4_t xA1, xB1;

    for (;;) {
        // phase even: prefetch adj(j+8)->slot0, gathers slot1, compute slot0
        {
            bool vA2 = j + 8 + e2 < re, vB2 = j + 10 + e2 < re;
            int nsA = adj[(unsigned)(vA2 ? j + 8 + e2 : 0)];
            int nsB = adj[(unsigned)(vB2 ? j + 10 + e2 : 0)];
            eA1 = lrelu(__half2float(as[(unsigned)sA1 * 8u + hh]) + adv);
            eB1 = lrelu(__half2float(as[(unsigned)sB1 * 8u + hh]) + adv);
            xA1 = xwv[(unsigned)sA1 * 8u + hh];
            xB1 = xwv[(unsigned)sB1 * 8u + hh];
            float wA = vA0 ? __builtin_amdgcn_exp2f(eA0 - shift) : 0.f;
            float wB = vB0 ? __builtin_amdgcn_exp2f(eB0 - shift) : 0.f;
            dsum += wA + wB;
            #pragma unroll
            for (int q = 0; q < 4; q++) {
                MIX_LO(accv[2 * q],     xA0[q], wA);
                MIX_HI(accv[2 * q + 1], xA0[q], wA);
            }
            #pragma unroll
            for (int q = 0; q < 4; q++) {
                MIX_LO(accv[2 * q],     xB0[q], wB);
                MIX_HI(accv[2 * q + 1], xB0[q], wB);
            }
            vA0 = vA2; vB0 = vB2; sA0 = nsA; sB0 = nsB;
        }
        j += 4;
        if (!__any(vA1)) break;
        // phase odd: prefetch adj(j+8)->slot1, gathers slot0, compute slot1
        {
            bool vA2 = j + 8 + e2 < re, vB2 = j + 10 + e2 < re;
            int nsA = adj[(unsigned)(vA2 ? j + 8 + e2 : 0)];
            int nsB = adj[(unsigned)(vB2 ? j + 10 + e2 : 0)];
            eA0 = lrelu(__half2float(as[(unsigned)sA0 * 8u + hh]) + adv);
            eB0 = lrelu(__half2float(as[(unsigned)sB0 * 8u + hh]) + adv);
            xA0 = xwv[(unsigned)sA0 * 8u + hh];
            xB0 = xwv[(unsigned)sB0 * 8u + hh];
            float wA = vA1 ? __builtin_amdgcn_exp2f(eA1 - shift) : 0.f;
            float wB = vB1 ? __builtin_amdgcn_exp2f(eB1 - shift) : 0.f;
            dsum += wA + wB;
            #pragma unroll
            for (int q = 0; q < 4; q++) {
                MIX_LO(accv[2 * q],     xA1[q], wA);
                MIX_HI(accv[2 * q + 1], xA1[q], wA);
            }
            #pragma unroll
            for (int q = 0; q < 4; q++) {
                MIX_LO(accv[2 * q],     xB1[q], wB);
                MIX_HI(accv[2 * q + 1], xB1[q], wB);
            }
            vA1 = vA2; vB1 = vB2; sA1 = nsA; sB1 = nsB;
        }
        j += 4;
        if (!__any(vA0)) break;
    }
    #pragma unroll
    for (int k = 0; k < 8; k++) accv[k] += __shfl_xor(accv[k], 8, 64);
    dsum += __shfl_xor(dsum, 8, 64);
    if (e2 == 0) {
        int nl = (threadIdx.x >> 4);                 // local node 0..31
        h8_t o;
        if (active) {
            float inv = 1.f / (1.f + dsum);          // self-loop weight = 1
            h8_t sv = *(const h8_t*)(xw + (size_t)n * 64 + hh * 8);
            float4 b0 = *(const float4*)(bias + hh * 8);
            float4 b1 = *(const float4*)(bias + hh * 8 + 4);
            float bb[8] = {b0.x, b0.y, b0.z, b0.w, b1.x, b1.y, b1.z, b1.w};
            #pragma unroll
            for (int k = 0; k < 8; k++) {
                float v = (accv[k] + (float)sv[k]) * inv + bb[k];
                o[k] = (_Float16)eluf(v);
            }
        } else {
            #pragma unroll
            for (int k = 0; k < 8; k++) o[k] = (_Float16)0.f;
        }
        hst[nl][hh] = o;
    }
    __syncthreads();
    // ---- fused TF1 across all 8 waves: wave w -> ct=w>>1 (cols), half=w&1 (rows)
    {
        int wave = threadIdx.x >> 6, lane = threadIdx.x & 63;
        int ct   = wave >> 1;
        int half = wave & 1;
        int quad = lane >> 4, c16 = lane & 15;
        int lrow = half * 16 + c16;                  // local row 0..31
        int row0 = blockIdx.x * 32 + half * 16;
        h8_t a0 = hst[lrow][quad];
        h8_t a1 = hst[lrow][4 + quad];
        int rbase = row0 + quad * 4;
        f4_t acc = {0.f, 0.f, 0.f, 0.f};
        acc = __builtin_amdgcn_mfma_f32_16x16x32_f16(a0, Wl[(ct * 2 + 0) * 64 + lane], acc, 0, 0, 0);
        acc = __builtin_amdgcn_mfma_f32_16x16x32_f16(a1, Wl[(ct * 2 + 1) * 64 + lane], acc, 0, 0, 0);
        float s1c = aS1[ct * 16 + c16];
        float d1c = aD1[ct * 16 + c16];
        int col = ct * 16 + c16;
        float ps[4], pd[4];
        #pragma unroll
        for (int r = 0; r < 4; r++) {
            int rr = rbase + r;
            if (rr < N) hw[(size_t)rr * 64 + col] = __float2half(acc[r]);
            ps[r] = acc[r] * s1c;
            pd[r] = acc[r] * d1c;
        }
        #pragma unroll
        for (int r = 0; r < 4; r++) {
            #pragma unroll
            for (int off = 1; off < 16; off <<= 1) {
                ps[r] += __shfl_xor(ps[r], off, 64);
                pd[r] += __shfl_xor(pd[r], off, 64);
            }
        }
        if (c16 == 0) {
            #pragma unroll
            for (int r = 0; r < 4; r++) {
                int lr = half * 16 + quad * 4 + r;
                psum[ct][lr]  = ps[r];
                pdsum[ct][lr] = pd[r];
            }
        }
    }
    __syncthreads();
    if (threadIdx.x < 32) {
        int lr = threadIdx.x;
        int rr = blockIdx.x * 32 + lr;
        if (rr < N) {
            float s  = psum[0][lr] + psum[1][lr] + psum[2][lr] + psum[3][lr];
            float dd = pdsum[0][lr] + pdsum[1][lr] + pdsum[2][lr] + pdsum[3][lr];
            as1[rr] = s * LOG2E;
            ad1[rr] = dd * LOG2E;
        }
    }
}

// ---------------- layer1 aggregation: 4 nodes/wave, depth-2 pipeline --------
__global__ __launch_bounds__(512) void k_agg1(
    const __half* __restrict__ hw, const float* __restrict__ as, const float* __restrict__ ad,
    const int* __restrict__ rowS, const int* __restrict__ rowE, const int* __restrict__ adj,
    const float* __restrict__ bias, int N, float* __restrict__ outp)
{
    int n = (blockIdx.x * 512 + threadIdx.x) >> 4;   // 32 nodes per block
    int sub  = threadIdx.x & 15;
    if (n >= N) return;
    int e2 = sub >> 3;
    int hh = sub & 7;
    int rs = rowS[n], re = rowE[n];
    const u4_t* hwv = (const u4_t*)hw;
    float adv = ad[n];
    float shift = lrelu(as[n] + adv);
    float accv[8];
    #pragma unroll
    for (int k = 0; k < 8; k++) accv[k] = 0.f;
    float dsum = 0.f;

    int j = rs;
    bool vA0 = j + e2 < re,     vB0 = j + 2 + e2 < re;
    int  sA0 = adj[(unsigned)(vA0 ? j + e2 : 0)];
    int  sB0 = adj[(unsigned)(vB0 ? j + 2 + e2 : 0)];
    bool vA1 = j + 4 + e2 < re, vB1 = j + 6 + e2 < re;
    int  sA1 = adj[(unsigned)(vA1 ? j + 4 + e2 : 0)];
    int  sB1 = adj[(unsigned)(vB1 ? j + 6 + e2 : 0)];
    float eA0 = lrelu(as[(unsigned)sA0] + adv);
    float eB0 = lrelu(as[(unsigned)sB0] + adv);
    u4_t xA0 = hwv[(unsigned)sA0 * 8u + hh];
    u4_t xB0 = hwv[(unsigned)sB0 * 8u + hh];
    float eA1, eB1; u4_t xA1, xB1;

    for (;;) {
        // phase even
        {
            bool vA2 = j + 8 + e2 < re, vB2 = j + 10 + e2 < re;
            int nsA = adj[(unsigned)(vA2 ? j + 8 + e2 : 0)];
            int nsB = adj[(unsigned)(vB2 ? j + 10 + e2 : 0)];
            eA1 = lrelu(as[(unsigned)sA1] + adv);
            eB1 = lrelu(as[(unsigned)sB1] + adv);
            xA1 = hwv[(unsigned)sA1 * 8u + hh];
            xB1 = hwv[(unsigned)sB1 * 8u + hh];
            float wA = vA0 ? __builtin_amdgcn_exp2f(eA0 - shift) : 0.f;
            float wB = vB0 ? __builtin_amdgcn_exp2f(eB0 - shift) : 0.f;
            dsum += wA + wB;
            #pragma unroll
            for (int q = 0; q < 4; q++) {
                MIX_LO(accv[2 * q],     xA0[q], wA);
                MIX_HI(accv[2 * q + 1], xA0[q], wA);
            }
            #pragma unroll
            for (int q = 0; q < 4; q++) {
                MIX_LO(accv[2 * q],     xB0[q], wB);
                MIX_HI(accv[2 * q + 1], xB0[q], wB);
            }
            vA0 = vA2; vB0 = vB2; sA0 = nsA; sB0 = nsB;
        }
        j += 4;
        if (!__any(vA1)) break;
        // phase odd
        {
            bool vA2 = j + 8 + e2 < re, vB2 = j + 10 + e2 < re;
            int nsA = adj[(unsigned)(vA2 ? j + 8 + e2 : 0)];
            int nsB = adj[(unsigned)(vB2 ? j + 10 + e2 : 0)];
            eA0 = lrelu(as[(unsigned)sA0] + adv);
            eB0 = lrelu(as[(unsigned)sB0] + adv);
            xA0 = hwv[(unsigned)sA0 * 8u + hh];
            xB0 = hwv[(unsigned)sB0 * 8u + hh];
            float wA = vA1 ? __builtin_amdgcn_exp2f(eA1 - shift) : 0.f;
            float wB = vB1 ? __builtin_amdgcn_exp2f(eB1 - shift) : 0.f;
            dsum += wA + wB;
            #pragma unroll
            for (int q = 0; q < 4; q++) {
                MIX_LO(accv[2 * q],     xA1[q], wA);
                MIX_HI(accv[2 * q + 1], xA1[q], wA);
            }
            #pragma unroll
            for (int q = 0; q < 4; q++) {
                MIX_LO(accv[2 * q],     xB1[q], wB);
                MIX_HI(accv[2 * q + 1], xB1[q], wB);
            }
            vA1 = vA2; vB1 = vB2; sA1 = nsA; sB1 = nsB;
        }
        j += 4;
        if (!__any(vA0)) break;
    }
    #pragma unroll
    for (int k = 0; k < 8; k++) accv[k] += __shfl_xor(accv[k], 8, 64);
    dsum += __shfl_xor(dsum, 8, 64);
    if (e2 == 0) {
        float inv = 1.f / (1.f + dsum);
        h8_t sv = *(const h8_t*)(hw + (size_t)n * 64 + hh * 8);
        float4 b0 = *(const float4*)(bias + hh * 8);
        float4 b1 = *(const float4*)(bias + hh * 8 + 4);
        float bb[8] = {b0.x, b0.y, b0.z, b0.w, b1.x, b1.y, b1.z, b1.w};
        float ov[8];
        #pragma unroll
        for (int k = 0; k < 8; k++)
            ov[k] = eluf((accv[k] + (float)sv[k]) * inv + bb[k]);
        float4 o0 = {ov[0], ov[1], ov[2], ov[3]};
        float4 o1 = {ov[4], ov[5], ov[6], ov[7]};
        float4* op = (float4*)(outp + (size_t)n * 64 + hh * 8);
        op[0] = o0;
        op[1] = o1;
    }
}

extern "C" void kernel_launch(void* const* d_in, const int* in_sizes, int n_in,
                              void* d_out, int out_size, void* d_ws, size_t ws_size,
                              hipStream_t stream)
{
    const float* x   = (const float*)d_in[0];
    const int*   ei  = (const int*)d_in[1];
    const float* W0  = (const float*)d_in[2];
    const float* aS0 = (const float*)d_in[3];
    const float* aD0 = (const float*)d_in[4];
    const float* b0  = (const float*)d_in[5];
    const float* W1  = (const float*)d_in[6];
    const float* aS1 = (const float*)d_in[7];
    const float* aD1 = (const float*)d_in[8];
    const float* b1  = (const float*)d_in[9];

    const int N = in_sizes[0] / 128;
    const int E = in_sizes[1] / 2;
    const int* srcp = ei;
    const int* dstp = ei + E;

    const int NB  = (N + 255) >> 8;          // 256-node buckets

    char* ws = (char*)d_ws;
    size_t off = 0;
    auto alloc = [&](size_t bytes) -> size_t {
        size_t o = off;
        off = (o + bytes + 255) & ~(size_t)255;
        return o;
    };
    __half* B1 = (__half*)(ws + alloc((size_t)N * 64 * 2));     // xw (half)
    size_t b2Bytes = (size_t)N * 64 * 2;
    size_t bkBytes = (size_t)NB * BINB * CELL * 4;              // 19.2 MB
    char*  region  = ws + alloc(b2Bytes > bkBytes ? b2Bytes : bkBytes);
    __half*   B2        = (__half*)region;     // hw overlays bucketBuf (dead after kP2)
    unsigned* bucketBuf = (unsigned*)region;
    __half* as0 = (__half*)(ws + alloc((size_t)N * 8 * 2));     // fp16 logits
    __half* ad0 = (__half*)(ws + alloc((size_t)N * 8 * 2));
    float* as1 = (float*)(ws + alloc((size_t)N * 4));
    float* ad1 = (float*)(ws + alloc((size_t)N * 4));
    int*  rowS = (int*)(ws + alloc((size_t)(N + 1) * 4));
    int*  rowE = (int*)(ws + alloc((size_t)(N + 1) * 4));
    int*   adj = (int*)(ws + alloc((size_t)NB * REGION * 4));
    int*  cntT = (int*)(ws + alloc((size_t)BINB * NBMAX * 4));

    const int gemmBlocks = (N + 127) / 128;
    const int binBlocks  = BINB;             // kP2 reads BINB cells per bucket
    const int perBlock   = (E + binBlocks - 1) / binBlocks;

    kGB<<<gemmBlocks + binBlocks, 512, 0, stream>>>(
        x, W0, aS0, aD0, N, B1, as0, ad0, gemmBlocks,
        srcp, dstp, E, perBlock, bucketBuf, cntT, NB, binBlocks);
    kP2<<<NB, 256, 0, stream>>>(bucketBuf, cntT, NB, N, rowS, rowE, adj);

    const int agBlocks = (N + 31) / 32;   // 32 nodes per 512-thread block
    // layer-0 aggregation + fused layer-1 transform:
    // reads xw (B1), writes hw (B2, over dead bucketBuf) + as1/ad1
    k_agg8<<<agBlocks, 512, 0, stream>>>(B1, as0, ad0, rowS, rowE, adj, b0,
                                         W1, aS1, aD1, N, B2, as1, ad1);
    // layer-1 aggregation
    k_agg1<<<agBlocks, 512, 0, stream>>>(B2, as1, ad1, rowS, rowE, adj, b1, N, (float*)d_out);
}